// Round 1
// 1062.155 us; speedup vs baseline: 1.4726x; 1.4726x over previous
//
#include <hip/hip_runtime.h>
#include <cstdint>
#include <cstddef>

// ---------- types ----------
typedef __attribute__((ext_vector_type(8))) __bf16 bf16x8;   // MFMA A/B frag (4 VGPRs)
typedef __attribute__((ext_vector_type(4))) float f32x4;     // MFMA C/D frag

__device__ __forceinline__ unsigned short f2bf(float f) {    // RNE float->bf16
  unsigned int u = __float_as_uint(f);
  u += 0x7FFFu + ((u >> 16) & 1u);
  return (unsigned short)(u >> 16);
}
__device__ __forceinline__ float bf2f(unsigned short h) {
  return __uint_as_float(((unsigned int)h) << 16);
}

// ---------- runtime dtype detection ----------
__device__ __forceinline__ int detect_f32(const unsigned short* det) {
  int cnt = 0;
#pragma unroll
  for (int i = 0; i < 32; ++i) {
    const unsigned int e = (det[2 * i] >> 7) & 0xFF;
    cnt += (e >= 115 && e <= 135) ? 1 : 0;
  }
  return cnt < 16;   // 1 => buffers are fp32, 0 => bf16
}

// dual-dtype scalar load/store (offsets in ELEMENTS)
__device__ __forceinline__ float loadf(const void* b, size_t i, int f32) {
  return f32 ? ((const float*)b)[i] : bf2f(((const unsigned short*)b)[i]);
}
__device__ __forceinline__ void storef(void* b, size_t i, float v, int f32) {
  if (f32) ((float*)b)[i] = v;
  else     ((unsigned short*)b)[i] = f2bf(v);
}
// dual-dtype 8-element fragment load -> bf16x8 (offset in ELEMENTS, 8-aligned)
// fp32 path is VECTORIZED: 2x dwordx4 instead of 8 scalar loads.
__device__ __forceinline__ bf16x8 load8(const void* base, size_t elem, int f32) {
  if (f32) {
    const float* p = (const float*)base + elem;
    const float4 a = *(const float4*)p;
    const float4 b = *(const float4*)(p + 4);
    bf16x8 r;
    unsigned short* q = (unsigned short*)&r;
    q[0] = f2bf(a.x); q[1] = f2bf(a.y); q[2] = f2bf(a.z); q[3] = f2bf(a.w);
    q[4] = f2bf(b.x); q[5] = f2bf(b.y); q[6] = f2bf(b.z); q[7] = f2bf(b.w);
    return r;
  }
  return *(const bf16x8*)((const unsigned short*)base + elem);
}

// ---------------------------------------------------------------------------
// GEMM: C[m,n] = sum_k A[m,k] * W[n,k]  (both K-contiguous, fp32 acc, MFMA bf16)
// 128x128 tile, BK=32, 256 thr = 4 waves, each wave 64x64 via 4x4 of 16x16x32.
// ---------------------------------------------------------------------------
__global__ __launch_bounds__(256) void gemm_bt_kernel(
    const void* __restrict__ A, const void* __restrict__ W, void* __restrict__ C,
    const unsigned short* __restrict__ det,
    int amode, int wmode, int cmode, size_t coff,
    int N, int K, int mode, int S, int t0)
{
  __shared__ __align__(16) unsigned short As[128 * 32];
  __shared__ __align__(16) unsigned short Bs[128 * 32];
  const int f32  = detect_f32(det);
  const int af32 = amode & f32, wf32 = wmode & f32, cf32 = cmode & f32;

  const int tid  = threadIdx.x;
  const int lane = tid & 63;
  const int wave = tid >> 6;
  const int quad = lane >> 4;
  const int l16  = lane & 15;
  const int mBase = blockIdx.x * 128;
  const int nBase = blockIdx.y * 128;
  const int wm = (wave >> 1) * 64;
  const int wn = (wave & 1) * 64;

  const int row0 = tid >> 2,          kc0 = (tid & 3) << 3;
  const int row1 = (256 + tid) >> 2,  kc1 = ((256 + tid) & 3) << 3;

  f32x4 acc[4][4];
#pragma unroll
  for (int i = 0; i < 4; ++i)
#pragma unroll
    for (int j = 0; j < 4; ++j) acc[i][j] = f32x4{0.f, 0.f, 0.f, 0.f};

  for (int kb = 0; kb < K; kb += 32) {
    const bf16x8 a0 = load8(A, (size_t)(mBase + row0) * K + kb + kc0, af32);
    const bf16x8 a1 = load8(A, (size_t)(mBase + row1) * K + kb + kc1, af32);
    const bf16x8 b0 = load8(W, (size_t)(nBase + row0) * K + kb + kc0, wf32);
    const bf16x8 b1 = load8(W, (size_t)(nBase + row1) * K + kb + kc1, wf32);
    __syncthreads();  // previous iteration's readers done
    *(bf16x8*)&As[(size_t)tid * 8]         = a0;
    *(bf16x8*)&As[(size_t)(256 + tid) * 8] = a1;
    *(bf16x8*)&Bs[(size_t)tid * 8]         = b0;
    *(bf16x8*)&Bs[(size_t)(256 + tid) * 8] = b1;
    __syncthreads();  // staging visible

    bf16x8 af[4], bfr[4];
#pragma unroll
    for (int i = 0; i < 4; ++i)
      af[i]  = *(const bf16x8*)&As[(wm + i * 16 + l16) * 32 + quad * 8];
#pragma unroll
    for (int j = 0; j < 4; ++j)
      bfr[j] = *(const bf16x8*)&Bs[(wn + j * 16 + l16) * 32 + quad * 8];
#pragma unroll
    for (int i = 0; i < 4; ++i)
#pragma unroll
      for (int j = 0; j < 4; ++j)
        acc[i][j] = __builtin_amdgcn_mfma_f32_16x16x32_bf16(af[i], bfr[j], acc[i][j], 0, 0, 0);
  }

  // epilogue: C/D layout col=lane&15, row=quad*4+reg
#pragma unroll
  for (int i = 0; i < 4; ++i) {
#pragma unroll
    for (int j = 0; j < 4; ++j) {
#pragma unroll
      for (int r = 0; r < 4; ++r) {
        const int m = mBase + wm + i * 16 + quad * 4 + r;
        const int n = nBase + wn + j * 16 + l16;
        size_t idx;
        if (mode == 0) {
          idx = (size_t)m * N + n;
        } else {
          const int b = m >> 8, t = m & 255;
          const int hh = n >> 6, d = n & 63;
          idx = (((size_t)(b * 32 + hh)) * S + (t0 + t)) * 64 + d;
        }
        storef(C, coff + idx, acc[i][j][r], cf32);
      }
    }
  }
}

// ---------------------------------------------------------------------------
// copy past slabs into outputs: new_{k,v}[0:256] = past_{k,v}[256:512].
// ---------------------------------------------------------------------------
__global__ __launch_bounds__(256) void copy_kernel(
    const void* __restrict__ past_k, const void* __restrict__ past_v,
    void* __restrict__ dout, const unsigned short* __restrict__ det)
{
  const int f32 = detect_f32(det);
  const int es  = f32 ? 4 : 2;
  const int bh  = blockIdx.x;
  const int tid = threadIdx.x;
  const size_t srcOff  = ((size_t)bh * 512 + 256) * 64 * es;
  const size_t dstKOff = ((size_t)8388608  + (size_t)bh * 512 * 64) * es;
  const size_t dstVOff = ((size_t)25165824 + (size_t)bh * 512 * 64) * es;
  const uint4* sK = (const uint4*)((const char*)past_k + srcOff);
  const uint4* sV = (const uint4*)((const char*)past_v + srcOff);
  uint4* dK = (uint4*)((char*)dout + dstKOff);
  uint4* dV = (uint4*)((char*)dout + dstVOff);
  const int n4 = 16384 * es / 16;  // slab = 256 rows * 64 elems
  for (int c = tid; c < n4; c += 256) { dK[c] = sK[c]; dV[c] = sV[c]; }
}

// ---------------------------------------------------------------------------
// RoPE: which=0 -> q_ws in-place (bf16 ws); which=1 -> new_k[256:] (in d_out,
// detected dtype) -> krot_ws (bf16).
// ---------------------------------------------------------------------------
__global__ __launch_bounds__(256) void rope_kernel(
    const int* __restrict__ pos_p,
    unsigned short* __restrict__ qbuf,
    const void* __restrict__ dout,
    unsigned short* __restrict__ krot,
    const unsigned short* __restrict__ det)
{
  const int f32 = detect_f32(det);
  const int gid = blockIdx.x * 256 + threadIdx.x;
  const int which = gid >> 22;               // 2^22 pairs per tensor
  const int pi = gid & ((1 << 22) - 1);
  const int i  = pi & 31;
  const int t  = (pi >> 5) & 255;
  const int bh = pi >> 13;
  const float pos  = (float)(*pos_p + t);
  const float freq = expf(-(float)i * 0.2878231366242557f);  // 10000^(-i/32)
  float sn, cs;
  sincosf(pos * freq, &sn, &cs);
  if (which == 0) {
    unsigned short* p = qbuf + (((size_t)bh * 256 + t) * 64 + 2 * i);
    const float a = bf2f(p[0]), b2 = bf2f(p[1]);
    p[0] = f2bf(a * cs - b2 * sn);
    p[1] = f2bf(a * sn + b2 * cs);
  } else {
    const size_t src = 8388608 + (((size_t)bh * 512 + 256 + t) * 64 + 2 * i);
    unsigned short* dp = krot + (((size_t)bh * 256 + t) * 64 + 2 * i);
    const float a = loadf(dout, src, f32), b2 = loadf(dout, src + 1, f32);
    dp[0] = f2bf(a * cs - b2 * sn);
    dp[1] = f2bf(a * sn + b2 * cs);
  }
}

// ---------------------------------------------------------------------------
// Flash-style attention, LDS-staged. One block per (b,h), 256 thr = 4 waves.
// Stage once per block:
//   K_lds[512][64] bf16, XOR-swizzled: byte = j*128 + ((d*2) ^ ((j&7)<<4))
//   Vt_lds[64][512] bf16 (transposed), byte = d*1024 + ((j*2) ^ (((d&7)^((d>>3)&7))<<4))
// Then each wave runs 4 independent 16-row strips of the flash loop entirely
// out of LDS. No barriers after the staging sync (P round-trip is
// wave-private; within-wave LDS ops are in-order, lgkmcnt(0) suffices).
// Mask: key j visible iff j <= t + 256.
// ---------------------------------------------------------------------------
__global__ __launch_bounds__(256, 1) void attn_kernel(
    const unsigned short* __restrict__ q,      // (BH,256,64) roped, bf16 ws
    const void* __restrict__ past_k,           // (BH,512,64) input dtype
    const unsigned short* __restrict__ k_rot,  // (BH,256,64) roped, bf16 ws
    const void* __restrict__ past_v,           // (BH,512,64) input dtype
    const void* __restrict__ dout,             // new_v at elem offset 25165824
    unsigned short* __restrict__ attn_out,     // (B,256,2048) bf16 ws
    const unsigned short* __restrict__ det)
{
  __shared__ __align__(16) unsigned short K_smem[512 * 64];   // 64 KiB, swizzled [j][d]
  __shared__ __align__(16) unsigned short Vt_smem[64 * 512];  // 64 KiB, swizzled [d][j]
  __shared__ __align__(16) unsigned short p_lds[4][16 * 32];  // 4 KiB wave-private P

  const int f32 = detect_f32(det);
  const int bh = blockIdx.x;
  const int b  = bh >> 5;
  const int h  = bh & 31;
  const int tid  = threadIdx.x;
  const int wave = tid >> 6;
  const int lane = tid & 63;
  const int quad = lane >> 4;
  const int l16  = lane & 15;
  const float NEG = -1e30f;

  const unsigned short* qb_ptr = q + (size_t)bh * 256 * 64;
  const unsigned short* krot   = k_rot + (size_t)bh * 256 * 64;
  const size_t kpastBase = ((size_t)bh * 512 + 256) * 64;  // elems into past_k
  const size_t vpastBase = ((size_t)bh * 512 + 256) * 64;  // elems into past_v
  const size_t vcurBase  = 25165824 + (size_t)bh * 512 * 64;  // elems into dout

  // ---- stage K (bf16, swizzled) and V^T (bf16, swizzled) ----
  // 512 rows x 64 elems, 8 elems per thread-chunk, 32 rows per iteration.
#pragma unroll 4
  for (int it = 0; it < 16; ++it) {
    const int lin = it * 256 + tid;
    const int j  = lin >> 3;          // key row 0..511
    const int d0 = (lin & 7) << 3;    // 8-elem chunk within row
    bf16x8 kv, vv;
    if (j < 256) {
      kv = load8(past_k, kpastBase + (size_t)j * 64 + d0, f32);
      vv = load8(past_v, vpastBase + (size_t)j * 64 + d0, f32);
    } else {
      kv = *(const bf16x8*)&krot[(size_t)(j - 256) * 64 + d0];
      vv = load8(dout, vcurBase + (size_t)j * 64 + d0, f32);
    }
    // K: b128 store, swizzle (j&7)<<4 on the intra-row byte offset
    *(bf16x8*)((char*)K_smem + (j * 128 + ((d0 * 2) ^ ((j & 7) << 4)))) = kv;
    // V^T: 8 scalar b16 stores; swizzle spreads (j, d) over all 32 banks
    const unsigned short* vs = (const unsigned short*)&vv;
    const int dh = (d0 >> 3) & 7;
    const int jx = j * 2;
#pragma unroll
    for (int i = 0; i < 8; ++i)
      *(unsigned short*)((char*)Vt_smem +
          ((d0 + i) * 1024 + (jx ^ ((i ^ dh) << 4)))) = vs[i];
  }
  __syncthreads();  // staging visible to all waves (only block-wide barrier)

  unsigned short* pw = p_lds[wave];
  volatile unsigned short* pwv = pw;

  for (int g = 0; g < 4; ++g) {
    // balanced strip assignment: every wave gets equal total key-pairs
    const int s = (g & 1) ? (g * 4 + 3 - wave) : (g * 4 + wave);
    const int qbase = s * 16;
    const bf16x8 aq0 = *(const bf16x8*)&qb_ptr[(qbase + l16) * 64 + quad * 8];
    const bf16x8 aq1 = *(const bf16x8*)&qb_ptr[(qbase + l16) * 64 + 32 + quad * 8];
    f32x4 o[4];
#pragma unroll
    for (int nt = 0; nt < 4; ++nt) o[nt] = f32x4{0.f, 0.f, 0.f, 0.f};
    float m_i[4], l_i[4];
#pragma unroll
    for (int r = 0; r < 4; ++r) { m_i[r] = NEG; l_i[r] = 0.f; }

    const int np = ((qbase + 271) >> 5) + 1;   // key pairs for this strip

    for (int p = 0; p < np; ++p) {
      const int j0 = p * 32;
      // ---- QK^T from K_smem ----
      f32x4 s0 = f32x4{0.f, 0.f, 0.f, 0.f};
      f32x4 s1 = f32x4{0.f, 0.f, 0.f, 0.f};
#pragma unroll
      for (int half = 0; half < 2; ++half) {
        const int j = j0 + half * 16 + l16;
        const int krow = j * 128;
        const int ksw  = (j & 7) << 4;
        const bf16x8 kb0 = *(const bf16x8*)((const char*)K_smem +
                           (krow + ((quad * 16) ^ ksw)));
        const bf16x8 kb1 = *(const bf16x8*)((const char*)K_smem +
                           (krow + ((64 + quad * 16) ^ ksw)));
        f32x4& sx = half ? s1 : s0;
        sx = __builtin_amdgcn_mfma_f32_16x16x32_bf16(aq0, kb0, sx, 0, 0, 0);
        sx = __builtin_amdgcn_mfma_f32_16x16x32_bf16(aq1, kb1, sx, 0, 0, 0);
      }
      // ---- online softmax (row = qbase + quad*4 + r; cols j0+{0,16}+l16) ----
#pragma unroll
      for (int r = 0; r < 4; ++r) {
        const int qrow = qbase + quad * 4 + r;
        float v0 = s0[r] * 0.125f;
        float v1 = s1[r] * 0.125f;
        if (j0 + l16 > qrow + 256)      v0 = NEG;
        if (j0 + 16 + l16 > qrow + 256) v1 = NEG;
        float t = fmaxf(v0, v1);
        t = fmaxf(t, __shfl_xor(t, 1));
        t = fmaxf(t, __shfl_xor(t, 2));
        t = fmaxf(t, __shfl_xor(t, 4));
        t = fmaxf(t, __shfl_xor(t, 8));
        const float mnew = fmaxf(m_i[r], t);
        const float alpha = __expf(m_i[r] - mnew);
        m_i[r] = mnew;
        const float p0 = __expf(v0 - mnew);
        const float p1 = __expf(v1 - mnew);
        float rs = p0 + p1;
        rs += __shfl_xor(rs, 1);
        rs += __shfl_xor(rs, 2);
        rs += __shfl_xor(rs, 4);
        rs += __shfl_xor(rs, 8);
        l_i[r] = l_i[r] * alpha + rs;
        pwv[(quad * 4 + r) * 32 + l16]      = f2bf(p0);
        pwv[(quad * 4 + r) * 32 + 16 + l16] = f2bf(p1);
#pragma unroll
        for (int nt = 0; nt < 4; ++nt) o[nt][r] *= alpha;
      }
      // wave-private P round trip: drain this wave's DS writes, then read
      asm volatile("s_waitcnt lgkmcnt(0)" ::: "memory");
      __builtin_amdgcn_sched_barrier(0);
      const bf16x8 ap = *(const bf16x8*)&pw[l16 * 32 + quad * 8];
      // ---- PV from Vt_smem (B-frag = 8 consecutive j at fixed d) ----
#pragma unroll
      for (int nt = 0; nt < 4; ++nt) {
        const int d = nt * 16 + l16;
        const int vsw = ((d & 7) ^ ((d >> 3) & 7)) << 4;
        const bf16x8 bv = *(const bf16x8*)((const char*)Vt_smem +
                          (d * 1024 + (((j0 + quad * 8) * 2) ^ vsw)));
        o[nt] = __builtin_amdgcn_mfma_f32_16x16x32_bf16(ap, bv, o[nt], 0, 0, 0);
      }
    }
    // epilogue: normalize, write (b, t, h*64 + nt*16 + l16) as bf16 ws
#pragma unroll
    for (int r = 0; r < 4; ++r) {
      const float inv = 1.0f / l_i[r];
      const int t = qbase + quad * 4 + r;
#pragma unroll
      for (int nt = 0; nt < 4; ++nt) {
        attn_out[((size_t)(b * 256 + t)) * 2048 + h * 64 + nt * 16 + l16] =
            f2bf(o[nt][r] * inv);
      }
    }
  }
}

// ---------------------------------------------------------------------------
extern "C" void kernel_launch(void* const* d_in, const int* in_sizes, int n_in,
                              void* d_out, int out_size, void* d_ws, size_t ws_size,
                              hipStream_t stream)
{
  const void* x      = d_in[0];
  const void* past_k = d_in[1];
  const void* past_v = d_in[2];
  const void* Wq     = d_in[3];
  const void* Wk     = d_in[4];
  const void* Wv     = d_in[5];
  const void* Wo     = d_in[6];
  const int* pos_p   = (const int*)d_in[7];
  const unsigned short* det = (const unsigned short*)x;  // dtype probe

  // workspace (always bf16 internally): 48 MiB
  unsigned short* ws      = (unsigned short*)d_ws;
  unsigned short* q_ws    = ws;                          // (BH,256,64)  16 MiB
  unsigned short* krot_ws = ws + 8388608;                // (BH,256,64)  16 MiB
  unsigned short* ao_ws   = ws + 16777216;               // (B,256,2048) 16 MiB

  const dim3 gg(32, 16), gb(256);
  // projections: Q -> bf16 ws scatter; K/V -> d_out (detected dtype) scatter
  hipLaunchKernelGGL(gemm_bt_kernel, gg, gb, 0, stream, x, Wq, (void*)q_ws, det,
                     1, 1, 0, (size_t)0,        2048, 2048, 1, 256, 0);
  hipLaunchKernelGGL(gemm_bt_kernel, gg, gb, 0, stream, x, Wk, d_out, det,
                     1, 1, 1, (size_t)8388608,  2048, 2048, 1, 512, 256);
  hipLaunchKernelGGL(gemm_bt_kernel, gg, gb, 0, stream, x, Wv, d_out, det,
                     1, 1, 1, (size_t)25165824, 2048, 2048, 1, 512, 256);
  // past slabs -> outputs
  hipLaunchKernelGGL(copy_kernel, dim3(512), gb, 0, stream, past_k, past_v, d_out, det);
  // RoPE: q in-place (bf16 ws); new_k[256:] (d_out) -> krot_ws (bf16)
  hipLaunchKernelGGL(rope_kernel, dim3(32768), gb, 0, stream, pos_p, q_ws, d_out, krot_ws, det);
  // attention -> ao_ws (bf16)
  hipLaunchKernelGGL(attn_kernel, dim3(512), gb, 0, stream,
                     q_ws, past_k, krot_ws, past_v, d_out, ao_ws, det);
  // output projection -> d_out (detected dtype)
  hipLaunchKernelGGL(gemm_bt_kernel, gg, gb, 0, stream, (const void*)ao_ws, Wo, d_out, det,
                     0, 1, 1, (size_t)0,        2048, 2048, 0, 0, 0);
}

// Round 2
// 673.942 us; speedup vs baseline: 2.3209x; 1.5760x over previous
//
#include <hip/hip_runtime.h>
#include <cstdint>
#include <cstddef>

// ---------- types ----------
typedef __attribute__((ext_vector_type(8))) __bf16 bf16x8;   // MFMA A/B frag (4 VGPRs)
typedef __attribute__((ext_vector_type(4))) float f32x4;     // MFMA C/D frag

typedef const __attribute__((address_space(1))) unsigned int* gas1_t;
typedef __attribute__((address_space(3))) unsigned int* las3_t;

__device__ __forceinline__ unsigned short f2bf(float f) {    // RNE float->bf16
  unsigned int u = __float_as_uint(f);
  u += 0x7FFFu + ((u >> 16) & 1u);
  return (unsigned short)(u >> 16);
}
__device__ __forceinline__ float bf2f(unsigned short h) {
  return __uint_as_float(((unsigned int)h) << 16);
}

// ---------- runtime dtype detection ----------
__device__ __forceinline__ int detect_f32(const unsigned short* det) {
  int cnt = 0;
#pragma unroll
  for (int i = 0; i < 32; ++i) {
    const unsigned int e = (det[2 * i] >> 7) & 0xFF;
    cnt += (e >= 115 && e <= 135) ? 1 : 0;
  }
  return cnt < 16;   // 1 => buffers are fp32, 0 => bf16
}

// dual-dtype scalar load/store (offsets in ELEMENTS)
__device__ __forceinline__ float loadf(const void* b, size_t i, int f32) {
  return f32 ? ((const float*)b)[i] : bf2f(((const unsigned short*)b)[i]);
}
__device__ __forceinline__ void storef(void* b, size_t i, float v, int f32) {
  if (f32) ((float*)b)[i] = v;
  else     ((unsigned short*)b)[i] = f2bf(v);
}
// dual-dtype 8-element fragment load -> bf16x8 (offset in ELEMENTS, 8-aligned)
// fp32 path is VECTORIZED: 2x dwordx4 instead of 8 scalar loads.
__device__ __forceinline__ bf16x8 load8(const void* base, size_t elem, int f32) {
  if (f32) {
    const float* p = (const float*)base + elem;
    const float4 a = *(const float4*)p;
    const float4 b = *(const float4*)(p + 4);
    bf16x8 r;
    unsigned short* q = (unsigned short*)&r;
    q[0] = f2bf(a.x); q[1] = f2bf(a.y); q[2] = f2bf(a.z); q[3] = f2bf(a.w);
    q[4] = f2bf(b.x); q[5] = f2bf(b.y); q[6] = f2bf(b.z); q[7] = f2bf(b.w);
    return r;
  }
  return *(const bf16x8*)((const unsigned short*)base + elem);
}

// ---------------------------------------------------------------------------
// convert_kernel: fp32 (or bf16) inputs -> bf16 workspace, one pass.
//   x   (4096x2048)           -> xb
//   Wq,Wk,Wv (each 2048x2048) -> wqkv (row-concat [6144][2048])
//   Wo  (2048x2048)           -> wob
// 4096 blocks x 256 thr x 3 chunks of 8 elems = 25,165,824 elems exactly.
// ---------------------------------------------------------------------------
__global__ __launch_bounds__(256) void convert_kernel(
    const void* __restrict__ x,  const void* __restrict__ wq,
    const void* __restrict__ wk, const void* __restrict__ wv,
    const void* __restrict__ wo,
    unsigned short* __restrict__ xb, unsigned short* __restrict__ wqkv,
    unsigned short* __restrict__ wob, const unsigned short* __restrict__ det)
{
  const int f32 = detect_f32(det);
  int c = blockIdx.x * 256 + threadIdx.x;
#pragma unroll
  for (int it = 0; it < 3; ++it, c += 1048576) {
    bf16x8 v; unsigned short* dp;
    if (c < 1048576) {
      v = load8(x, (size_t)c << 3, f32);                     dp = xb   + ((size_t)c << 3);
    } else if (c < 1572864) {
      v = load8(wq, (size_t)(c - 1048576) << 3, f32);        dp = wqkv + ((size_t)(c - 1048576) << 3);
    } else if (c < 2097152) {
      v = load8(wk, (size_t)(c - 1572864) << 3, f32);        dp = wqkv + 4194304 + ((size_t)(c - 1572864) << 3);
    } else if (c < 2621440) {
      v = load8(wv, (size_t)(c - 2097152) << 3, f32);        dp = wqkv + 8388608 + ((size_t)(c - 2097152) << 3);
    } else {
      v = load8(wo, (size_t)(c - 2621440) << 3, f32);        dp = wob  + ((size_t)(c - 2621440) << 3);
    }
    *(bf16x8*)dp = v;
  }
}

// ---------------------------------------------------------------------------
// gemm_bf16_kernel: C[m,n] = sum_k A[m,k]*W[n,k], A/W bf16, K=2048 fixed.
// 128x128 tile, BK=64, 256 thr = 4 waves, wave = 64x64 via 4x4 of 16x16x32.
// Staging: global_load_lds width 16 (linear LDS dest). LDS XOR swizzle
// chunk ^= (row&7) on 16B chunks within the 128B row -- applied on the
// SOURCE address (pre-swizzle) and the ds_read address (rule #21) so
// fragment reads are ~2-way (free) instead of 16-way bank-conflicted.
// XCD-chunked block swizzle (gridDim.x % 8 == 0 guaranteed by launches).
// route 0: C -> c0 at m*2048+n, detected dtype.
// route 1: fused QKV epilogue. n segment (n>>11, uniform per block):
//   0: Q -> c0 (q_ws, bf16) scatter ((b*32+h)*256 + t)*64 + d
//   1: K -> dko + 8388608, detected dtype, ((b*32+h)*512 + 256+t)*64 + d
//   2: V -> dko + 25165824, same layout
// ---------------------------------------------------------------------------
__global__ __launch_bounds__(256) void gemm_bf16_kernel(
    const unsigned short* __restrict__ A,   // [M][2048] bf16
    const unsigned short* __restrict__ W,   // [N][2048] bf16
    void* __restrict__ c0,
    void* __restrict__ dko,
    const unsigned short* __restrict__ det,
    int route)
{
  __shared__ __align__(16) unsigned short As[128 * 64];  // 16 KiB
  __shared__ __align__(16) unsigned short Bs[128 * 64];  // 16 KiB
  const int f32 = detect_f32(det);

  const int tid  = threadIdx.x;
  const int lane = tid & 63;
  const int wave = tid >> 6;
  const int quad = lane >> 4;
  const int l16  = lane & 15;

  // XCD-chunked swizzle (bijective since gridDim.x % 8 == 0)
  const int qq  = gridDim.x >> 3;
  const int swz = (blockIdx.x & 7) * qq + (blockIdx.x >> 3);
  const int mBase = (swz & 31) * 128;
  const int nBase = (swz >> 5) * 128;

  const int wm = (wave >> 1) * 64;
  const int wn = (wave & 1) * 64;
  const int r0w  = wave * 32;          // this wave stages rows [r0w, r0w+32)
  const int lrow = lane >> 3;          // 0..7 within 8-row slab
  const int lch  = (lane & 7) ^ lrow;  // pre-swizzled source chunk (constant/lane)

  f32x4 acc[4][4];
#pragma unroll
  for (int i = 0; i < 4; ++i)
#pragma unroll
    for (int j = 0; j < 4; ++j) acc[i][j] = f32x4{0.f, 0.f, 0.f, 0.f};

  const unsigned short* Abase = A + (size_t)mBase * 2048;
  const unsigned short* Wbase = W + (size_t)nBase * 2048;
  const int sa = l16 & 7;              // read-side swizzle key

  for (int kb = 0; kb < 2048; kb += 64) {
    __syncthreads();   // previous iteration's ds_reads done before overwrite
#pragma unroll
    for (int ii = 0; ii < 4; ++ii) {
      const int r0 = r0w + ii * 8;
      const size_t goff = (size_t)(r0 + lrow) * 2048 + kb + lch * 8;
      __builtin_amdgcn_global_load_lds((gas1_t)(Abase + goff),
                                       (las3_t)(As + r0 * 64), 16, 0, 0);
      __builtin_amdgcn_global_load_lds((gas1_t)(Wbase + goff),
                                       (las3_t)(Bs + r0 * 64), 16, 0, 0);
    }
    __syncthreads();   // staged data visible (compiler drains vmcnt)

    bf16x8 af[2][4], bfr[2][4];
#pragma unroll
    for (int i = 0; i < 4; ++i) {
      const char* pa = (const char*)As + (wm + i * 16 + l16) * 128;
      const char* pb = (const char*)Bs + (wn + i * 16 + l16) * 128;
      af[0][i]  = *(const bf16x8*)(pa + ((quad ^ sa) << 4));
      af[1][i]  = *(const bf16x8*)(pa + (((quad + 4) ^ sa) << 4));
      bfr[0][i] = *(const bf16x8*)(pb + ((quad ^ sa) << 4));
      bfr[1][i] = *(const bf16x8*)(pb + (((quad + 4) ^ sa) << 4));
    }
#pragma unroll
    for (int kk = 0; kk < 2; ++kk)
#pragma unroll
      for (int i = 0; i < 4; ++i)
#pragma unroll
        for (int j = 0; j < 4; ++j)
          acc[i][j] = __builtin_amdgcn_mfma_f32_16x16x32_bf16(af[kk][i], bfr[kk][j], acc[i][j], 0, 0, 0);
  }

  // epilogue: C/D layout col=lane&15, row=quad*4+reg
#pragma unroll
  for (int i = 0; i < 4; ++i) {
#pragma unroll
    for (int j = 0; j < 4; ++j) {
#pragma unroll
      for (int r = 0; r < 4; ++r) {
        const int m = mBase + wm + i * 16 + quad * 4 + r;
        const int n = nBase + wn + j * 16 + l16;
        if (route == 0) {
          storef(c0, (size_t)m * 2048 + n, acc[i][j][r], f32);
        } else {
          const int b = m >> 8, t = m & 255;
          const int seg = n >> 11;         // uniform per block (2048 % 128 == 0)
          const int nn = n & 2047;
          const int hh = nn >> 6, d = nn & 63;
          if (seg == 0) {
            ((unsigned short*)c0)[(((size_t)(b * 32 + hh)) * 256 + t) * 64 + d] =
                f2bf(acc[i][j][r]);
          } else {
            const size_t coff = (seg == 1) ? (size_t)8388608 : (size_t)25165824;
            storef(dko, coff + (((size_t)(b * 32 + hh)) * 512 + 256 + t) * 64 + d,
                   acc[i][j][r], f32);
          }
        }
      }
    }
  }
}

// ---------------------------------------------------------------------------
// LEGACY GEMM (round-1) -- fallback when workspace < 64 MiB.
// ---------------------------------------------------------------------------
__global__ __launch_bounds__(256) void gemm_bt_kernel(
    const void* __restrict__ A, const void* __restrict__ W, void* __restrict__ C,
    const unsigned short* __restrict__ det,
    int amode, int wmode, int cmode, size_t coff,
    int N, int K, int mode, int S, int t0)
{
  __shared__ __align__(16) unsigned short As[128 * 32];
  __shared__ __align__(16) unsigned short Bs[128 * 32];
  const int f32  = detect_f32(det);
  const int af32 = amode & f32, wf32 = wmode & f32, cf32 = cmode & f32;

  const int tid  = threadIdx.x;
  const int lane = tid & 63;
  const int wave = tid >> 6;
  const int quad = lane >> 4;
  const int l16  = lane & 15;
  const int mBase = blockIdx.x * 128;
  const int nBase = blockIdx.y * 128;
  const int wm = (wave >> 1) * 64;
  const int wn = (wave & 1) * 64;

  const int row0 = tid >> 2,          kc0 = (tid & 3) << 3;
  const int row1 = (256 + tid) >> 2,  kc1 = ((256 + tid) & 3) << 3;

  f32x4 acc[4][4];
#pragma unroll
  for (int i = 0; i < 4; ++i)
#pragma unroll
    for (int j = 0; j < 4; ++j) acc[i][j] = f32x4{0.f, 0.f, 0.f, 0.f};

  for (int kb = 0; kb < K; kb += 32) {
    const bf16x8 a0 = load8(A, (size_t)(mBase + row0) * K + kb + kc0, af32);
    const bf16x8 a1 = load8(A, (size_t)(mBase + row1) * K + kb + kc1, af32);
    const bf16x8 b0 = load8(W, (size_t)(nBase + row0) * K + kb + kc0, wf32);
    const bf16x8 b1 = load8(W, (size_t)(nBase + row1) * K + kb + kc1, wf32);
    __syncthreads();
    *(bf16x8*)&As[(size_t)tid * 8]         = a0;
    *(bf16x8*)&As[(size_t)(256 + tid) * 8] = a1;
    *(bf16x8*)&Bs[(size_t)tid * 8]         = b0;
    *(bf16x8*)&Bs[(size_t)(256 + tid) * 8] = b1;
    __syncthreads();

    bf16x8 af[4], bfr[4];
#pragma unroll
    for (int i = 0; i < 4; ++i)
      af[i]  = *(const bf16x8*)&As[(wm + i * 16 + l16) * 32 + quad * 8];
#pragma unroll
    for (int j = 0; j < 4; ++j)
      bfr[j] = *(const bf16x8*)&Bs[(wn + j * 16 + l16) * 32 + quad * 8];
#pragma unroll
    for (int i = 0; i < 4; ++i)
#pragma unroll
      for (int j = 0; j < 4; ++j)
        acc[i][j] = __builtin_amdgcn_mfma_f32_16x16x32_bf16(af[i], bfr[j], acc[i][j], 0, 0, 0);
  }

#pragma unroll
  for (int i = 0; i < 4; ++i) {
#pragma unroll
    for (int j = 0; j < 4; ++j) {
#pragma unroll
      for (int r = 0; r < 4; ++r) {
        const int m = mBase + wm + i * 16 + quad * 4 + r;
        const int n = nBase + wn + j * 16 + l16;
        size_t idx;
        if (mode == 0) {
          idx = (size_t)m * N + n;
        } else {
          const int b = m >> 8, t = m & 255;
          const int hh = n >> 6, d = n & 63;
          idx = (((size_t)(b * 32 + hh)) * S + (t0 + t)) * 64 + d;
        }
        storef(C, coff + idx, acc[i][j][r], cf32);
      }
    }
  }
}

// ---------------------------------------------------------------------------
// copy past slabs into outputs: new_{k,v}[0:256] = past_{k,v}[256:512].
// ---------------------------------------------------------------------------
__global__ __launch_bounds__(256) void copy_kernel(
    const void* __restrict__ past_k, const void* __restrict__ past_v,
    void* __restrict__ dout, const unsigned short* __restrict__ det)
{
  const int f32 = detect_f32(det);
  const int es  = f32 ? 4 : 2;
  const int bh  = blockIdx.x;
  const int tid = threadIdx.x;
  const size_t srcOff  = ((size_t)bh * 512 + 256) * 64 * es;
  const size_t dstKOff = ((size_t)8388608  + (size_t)bh * 512 * 64) * es;
  const size_t dstVOff = ((size_t)25165824 + (size_t)bh * 512 * 64) * es;
  const uint4* sK = (const uint4*)((const char*)past_k + srcOff);
  const uint4* sV = (const uint4*)((const char*)past_v + srcOff);
  uint4* dK = (uint4*)((char*)dout + dstKOff);
  uint4* dV = (uint4*)((char*)dout + dstVOff);
  const int n4 = 16384 * es / 16;
  for (int c = tid; c < n4; c += 256) { dK[c] = sK[c]; dV[c] = sV[c]; }
}

// ---------------------------------------------------------------------------
// RoPE: which=0 -> q_ws in-place (bf16 ws); which=1 -> new_k[256:] (in d_out,
// detected dtype) -> krot_ws (bf16).
// ---------------------------------------------------------------------------
__global__ __launch_bounds__(256) void rope_kernel(
    const int* __restrict__ pos_p,
    unsigned short* __restrict__ qbuf,
    const void* __restrict__ dout,
    unsigned short* __restrict__ krot,
    const unsigned short* __restrict__ det)
{
  const int f32 = detect_f32(det);
  const int gid = blockIdx.x * 256 + threadIdx.x;
  const int which = gid >> 22;
  const int pi = gid & ((1 << 22) - 1);
  const int i  = pi & 31;
  const int t  = (pi >> 5) & 255;
  const int bh = pi >> 13;
  const float pos  = (float)(*pos_p + t);
  const float freq = expf(-(float)i * 0.2878231366242557f);
  float sn, cs;
  sincosf(pos * freq, &sn, &cs);
  if (which == 0) {
    unsigned short* p = qbuf + (((size_t)bh * 256 + t) * 64 + 2 * i);
    const float a = bf2f(p[0]), b2 = bf2f(p[1]);
    p[0] = f2bf(a * cs - b2 * sn);
    p[1] = f2bf(a * sn + b2 * cs);
  } else {
    const size_t src = 8388608 + (((size_t)bh * 512 + 256 + t) * 64 + 2 * i);
    unsigned short* dp = krot + (((size_t)bh * 256 + t) * 64 + 2 * i);
    const float a = loadf(dout, src, f32), b2 = loadf(dout, src + 1, f32);
    dp[0] = f2bf(a * cs - b2 * sn);
    dp[1] = f2bf(a * sn + b2 * cs);
  }
}

// ---------------------------------------------------------------------------
// Flash-style attention, LDS-staged (round-1 version, unchanged).
// ---------------------------------------------------------------------------
__global__ __launch_bounds__(256, 1) void attn_kernel(
    const unsigned short* __restrict__ q,
    const void* __restrict__ past_k,
    const unsigned short* __restrict__ k_rot,
    const void* __restrict__ past_v,
    const void* __restrict__ dout,
    unsigned short* __restrict__ attn_out,
    const unsigned short* __restrict__ det)
{
  __shared__ __align__(16) unsigned short K_smem[512 * 64];
  __shared__ __align__(16) unsigned short Vt_smem[64 * 512];
  __shared__ __align__(16) unsigned short p_lds[4][16 * 32];

  const int f32 = detect_f32(det);
  const int bh = blockIdx.x;
  const int b  = bh >> 5;
  const int h  = bh & 31;
  const int tid  = threadIdx.x;
  const int wave = tid >> 6;
  const int lane = tid & 63;
  const int quad = lane >> 4;
  const int l16  = lane & 15;
  const float NEG = -1e30f;

  const unsigned short* qb_ptr = q + (size_t)bh * 256 * 64;
  const unsigned short* krot   = k_rot + (size_t)bh * 256 * 64;
  const size_t kpastBase = ((size_t)bh * 512 + 256) * 64;
  const size_t vpastBase = ((size_t)bh * 512 + 256) * 64;
  const size_t vcurBase  = 25165824 + (size_t)bh * 512 * 64;

#pragma unroll 4
  for (int it = 0; it < 16; ++it) {
    const int lin = it * 256 + tid;
    const int j  = lin >> 3;
    const int d0 = (lin & 7) << 3;
    bf16x8 kv, vv;
    if (j < 256) {
      kv = load8(past_k, kpastBase + (size_t)j * 64 + d0, f32);
      vv = load8(past_v, vpastBase + (size_t)j * 64 + d0, f32);
    } else {
      kv = *(const bf16x8*)&krot[(size_t)(j - 256) * 64 + d0];
      vv = load8(dout, vcurBase + (size_t)j * 64 + d0, f32);
    }
    *(bf16x8*)((char*)K_smem + (j * 128 + ((d0 * 2) ^ ((j & 7) << 4)))) = kv;
    const unsigned short* vs = (const unsigned short*)&vv;
    const int dh = (d0 >> 3) & 7;
    const int jx = j * 2;
#pragma unroll
    for (int i = 0; i < 8; ++i)
      *(unsigned short*)((char*)Vt_smem +
          ((d0 + i) * 1024 + (jx ^ ((i ^ dh) << 4)))) = vs[i];
  }
  __syncthreads();

  unsigned short* pw = p_lds[wave];
  volatile unsigned short* pwv = pw;

  for (int g = 0; g < 4; ++g) {
    const int s = (g & 1) ? (g * 4 + 3 - wave) : (g * 4 + wave);
    const int qbase = s * 16;
    const bf16x8 aq0 = *(const bf16x8*)&qb_ptr[(qbase + l16) * 64 + quad * 8];
    const bf16x8 aq1 = *(const bf16x8*)&qb_ptr[(qbase + l16) * 64 + 32 + quad * 8];
    f32x4 o[4];
#pragma unroll
    for (int nt = 0; nt < 4; ++nt) o[nt] = f32x4{0.f, 0.f, 0.f, 0.f};
    float m_i[4], l_i[4];
#pragma unroll
    for (int r = 0; r < 4; ++r) { m_i[r] = NEG; l_i[r] = 0.f; }

    const int np = ((qbase + 271) >> 5) + 1;

    for (int p = 0; p < np; ++p) {
      const int j0 = p * 32;
      f32x4 s0 = f32x4{0.f, 0.f, 0.f, 0.f};
      f32x4 s1 = f32x4{0.f, 0.f, 0.f, 0.f};
#pragma unroll
      for (int half = 0; half < 2; ++half) {
        const int j = j0 + half * 16 + l16;
        const int krow = j * 128;
        const int ksw  = (j & 7) << 4;
        const bf16x8 kb0 = *(const bf16x8*)((const char*)K_smem +
                           (krow + ((quad * 16) ^ ksw)));
        const bf16x8 kb1 = *(const bf16x8*)((const char*)K_smem +
                           (krow + ((64 + quad * 16) ^ ksw)));
        f32x4& sx = half ? s1 : s0;
        sx = __builtin_amdgcn_mfma_f32_16x16x32_bf16(aq0, kb0, sx, 0, 0, 0);
        sx = __builtin_amdgcn_mfma_f32_16x16x32_bf16(aq1, kb1, sx, 0, 0, 0);
      }
#pragma unroll
      for (int r = 0; r < 4; ++r) {
        const int qrow = qbase + quad * 4 + r;
        float v0 = s0[r] * 0.125f;
        float v1 = s1[r] * 0.125f;
        if (j0 + l16 > qrow + 256)      v0 = NEG;
        if (j0 + 16 + l16 > qrow + 256) v1 = NEG;
        float t = fmaxf(v0, v1);
        t = fmaxf(t, __shfl_xor(t, 1));
        t = fmaxf(t, __shfl_xor(t, 2));
        t = fmaxf(t, __shfl_xor(t, 4));
        t = fmaxf(t, __shfl_xor(t, 8));
        const float mnew = fmaxf(m_i[r], t);
        const float alpha = __expf(m_i[r] - mnew);
        m_i[r] = mnew;
        const float p0 = __expf(v0 - mnew);
        const float p1 = __expf(v1 - mnew);
        float rs = p0 + p1;
        rs += __shfl_xor(rs, 1);
        rs += __shfl_xor(rs, 2);
        rs += __shfl_xor(rs, 4);
        rs += __shfl_xor(rs, 8);
        l_i[r] = l_i[r] * alpha + rs;
        pwv[(quad * 4 + r) * 32 + l16]      = f2bf(p0);
        pwv[(quad * 4 + r) * 32 + 16 + l16] = f2bf(p1);
#pragma unroll
        for (int nt = 0; nt < 4; ++nt) o[nt][r] *= alpha;
      }
      asm volatile("s_waitcnt lgkmcnt(0)" ::: "memory");
      __builtin_amdgcn_sched_barrier(0);
      const bf16x8 ap = *(const bf16x8*)&pw[l16 * 32 + quad * 8];
#pragma unroll
      for (int nt = 0; nt < 4; ++nt) {
        const int d = nt * 16 + l16;
        const int vsw = ((d & 7) ^ ((d >> 3) & 7)) << 4;
        const bf16x8 bv = *(const bf16x8*)((const char*)Vt_smem +
                          (d * 1024 + (((j0 + quad * 8) * 2) ^ vsw)));
        o[nt] = __builtin_amdgcn_mfma_f32_16x16x32_bf16(ap, bv, o[nt], 0, 0, 0);
      }
    }
#pragma unroll
    for (int r = 0; r < 4; ++r) {
      const float inv = 1.0f / l_i[r];
      const int t = qbase + quad * 4 + r;
#pragma unroll
      for (int nt = 0; nt < 4; ++nt) {
        attn_out[((size_t)(b * 256 + t)) * 2048 + h * 64 + nt * 16 + l16] =
            f2bf(o[nt][r] * inv);
      }
    }
  }
}

// ---------------------------------------------------------------------------
extern "C" void kernel_launch(void* const* d_in, const int* in_sizes, int n_in,
                              void* d_out, int out_size, void* d_ws, size_t ws_size,
                              hipStream_t stream)
{
  const void* x      = d_in[0];
  const void* past_k = d_in[1];
  const void* past_v = d_in[2];
  const void* Wq     = d_in[3];
  const void* Wk     = d_in[4];
  const void* Wv     = d_in[5];
  const void* Wo     = d_in[6];
  const int* pos_p   = (const int*)d_in[7];
  const unsigned short* det = (const unsigned short*)x;

  unsigned short* ws = (unsigned short*)d_ws;
  const dim3 gb(256);

  if (ws_size >= (size_t)67108864) {
    // ---- 64 MiB aliased layout (elements) ----
    // [0,        8388608)  q_ws
    // [8388608, 16777216)  xb (dead after QKV gemm)  ∪  ao_ws (born at attn)
    // [16777216,29360128)  wqkv (dead after QKV gemm); krot_ws aliases head
    // [29360128,33554432)  wob
    unsigned short* q_ws    = ws;
    unsigned short* xb      = ws + 8388608;
    unsigned short* ao_ws   = ws + 8388608;
    unsigned short* wqkv    = ws + 16777216;
    unsigned short* krot_ws = ws + 16777216;
    unsigned short* wob     = ws + 29360128;

    hipLaunchKernelGGL(convert_kernel, dim3(4096), gb, 0, stream,
                       x, Wq, Wk, Wv, Wo, xb, wqkv, wob, det);
    // fused QKV: M=4096, N=6144 -> 1536 blocks (6/CU)
    hipLaunchKernelGGL(gemm_bf16_kernel, dim3(1536), gb, 0, stream,
                       xb, wqkv, (void*)q_ws, d_out, det, 1);
    hipLaunchKernelGGL(copy_kernel, dim3(512), gb, 0, stream, past_k, past_v, d_out, det);
    hipLaunchKernelGGL(rope_kernel, dim3(32768), gb, 0, stream, pos_p, q_ws, d_out, krot_ws, det);
    hipLaunchKernelGGL(attn_kernel, dim3(512), gb, 0, stream,
                       q_ws, past_k, krot_ws, past_v, d_out, ao_ws, det);
    // output projection: M=4096, N=2048 -> 512 blocks
    hipLaunchKernelGGL(gemm_bf16_kernel, dim3(512), gb, 0, stream,
                       ao_ws, wob, d_out, d_out, det, 0);
  } else {
    // ---- legacy 48 MiB path (round-1 behavior) ----
    unsigned short* q_ws    = ws;
    unsigned short* krot_ws = ws + 8388608;
    unsigned short* ao_ws   = ws + 16777216;
    const dim3 gg(32, 16);
    hipLaunchKernelGGL(gemm_bt_kernel, gg, gb, 0, stream, x, Wq, (void*)q_ws, det,
                       1, 1, 0, (size_t)0,        2048, 2048, 1, 256, 0);
    hipLaunchKernelGGL(gemm_bt_kernel, gg, gb, 0, stream, x, Wk, d_out, det,
                       1, 1, 1, (size_t)8388608,  2048, 2048, 1, 512, 256);
    hipLaunchKernelGGL(gemm_bt_kernel, gg, gb, 0, stream, x, Wv, d_out, det,
                       1, 1, 1, (size_t)25165824, 2048, 2048, 1, 512, 256);
    hipLaunchKernelGGL(copy_kernel, dim3(512), gb, 0, stream, past_k, past_v, d_out, det);
    hipLaunchKernelGGL(rope_kernel, dim3(32768), gb, 0, stream, pos_p, q_ws, d_out, krot_ws, det);
    hipLaunchKernelGGL(attn_kernel, dim3(512), gb, 0, stream,
                       q_ws, past_k, krot_ws, past_v, d_out, ao_ws, det);
    hipLaunchKernelGGL(gemm_bt_kernel, gg, gb, 0, stream, (const void*)ao_ws, Wo, d_out, det,
                       0, 1, 1, (size_t)0,        2048, 2048, 0, 0, 0);
  }
}